// Round 3
// baseline (80.143 us; speedup 1.0000x reference)
//
#include <hip/hip_runtime.h>

// DeepPoly affine transformer — fused single pass over weight.
// Identity: Wp@x + Wm@y = 0.5*( W@(x+y) - |W|@(y-x) )
//           Wp@y + Wm@x = 0.5*( W@(x+y) + |W|@(y-x) )
// mu folded: new_lower = bias + sum( wp*A + wm*B ), A=beta*l0, B=lmbda*u0+mu
//            new_upper = bias + sum( wp*B + wm*A )
// Per weight element: 1 abs + 4 FMA against 4 precomputed column streams.
// R3: ROWS 4->8 (halves column-stream re-reads), BLK 256->512,
//     __launch_bounds__(512,4) to force VGPR<=128 (4 waves/SIMD).

constexpr int N_OUT = 4096;
constexpr int N_IN  = 8192;
constexpr int BLK   = 512;             // 8 waves
constexpr int ROWS  = 8;               // output rows per block
constexpr int KITER = N_IN / 4 / BLK;  // 4 float4 chunks per thread

__device__ __forceinline__ float4 ld4(const float* p) {
    return *reinterpret_cast<const float4*>(p);
}

__device__ __forceinline__ float waveRed(float v) {
#pragma unroll
    for (int off = 32; off > 0; off >>= 1)
        v += __shfl_xor(v, off, 64);
    return v;
}

// ---- pass 1: build the 4 fused column vectors into workspace ----
__global__ __launch_bounds__(256) void precompute_cols(
        const float* __restrict__ bounds,   // [2, N_IN]
        const float* __restrict__ bounds0,  // [2, N_IN]
        const float* __restrict__ beta,
        const float* __restrict__ lmbda,
        const float* __restrict__ mu,
        float* __restrict__ cols)           // [4, N_IN] in d_ws
{
    const int i = blockIdx.x * 256 + threadIdx.x;
    if (i >= N_IN) return;
    const float l  = bounds[i],  u  = bounds[i + N_IN];
    const float l0 = bounds0[i], u0 = bounds0[i + N_IN];
    const float A  = beta[i] * l0;
    const float B  = fmaf(lmbda[i], u0, mu[i]);
    cols[i]             = l + u;   // s1
    cols[i + N_IN]      = u - l;   // d1  (>= 0)
    cols[i + 2 * N_IN]  = A + B;   // s2
    cols[i + 3 * N_IN]  = B - A;   // d2
}

// ---- pass 2: stream the weight once ----
__global__ __launch_bounds__(BLK, 4) void deeppoly_main(
        const float* __restrict__ W,
        const float* __restrict__ bias,
        const float* __restrict__ cols,
        float* __restrict__ out)            // [2, N_OUT]
{
    const int t  = threadIdx.x;
    const int r0 = blockIdx.x * ROWS;

    const float* s1 = cols;
    const float* d1 = cols + N_IN;
    const float* s2 = cols + 2 * N_IN;
    const float* d2 = cols + 3 * N_IN;

    float aS[ROWS], aD[ROWS], aMS[ROWS], aMD[ROWS];
#pragma unroll
    for (int r = 0; r < ROWS; ++r) {
        aS[r] = 0.f; aD[r] = 0.f; aMS[r] = 0.f; aMD[r] = 0.f;
    }

#pragma unroll
    for (int k = 0; k < KITER; ++k) {
        const int c = (t + k * BLK) * 4;

        const float4 s1v = ld4(s1 + c);
        const float4 d1v = ld4(d1 + c);
        const float4 s2v = ld4(s2 + c);
        const float4 d2v = ld4(d2 + c);

#pragma unroll
        for (int r = 0; r < ROWS; ++r) {
            const float4 wv = ld4(W + (size_t)(r0 + r) * N_IN + c);

#define UPD(wc, s1c, d1c, s2c, d2c)                      \
            {                                            \
                const float w_ = (wc);                   \
                const float a_ = fabsf(w_);              \
                aS[r]  = fmaf(w_, (s1c), aS[r]);         \
                aD[r]  = fmaf(a_, (d1c), aD[r]);         \
                aMS[r] = fmaf(w_, (s2c), aMS[r]);        \
                aMD[r] = fmaf(a_, (d2c), aMD[r]);        \
            }
            UPD(wv.x, s1v.x, d1v.x, s2v.x, d2v.x)
            UPD(wv.y, s1v.y, d1v.y, s2v.y, d2v.y)
            UPD(wv.z, s1v.z, d1v.z, s2v.z, d2v.z)
            UPD(wv.w, s1v.w, d1v.w, s2v.w, d2v.w)
#undef UPD
        }
    }

    // ---- block reduction: wave shuffle-reduce, then LDS across 8 waves ----
    __shared__ float red[BLK / 64][ROWS][4];
    const int wave = t >> 6;
    const int lane = t & 63;

#pragma unroll
    for (int r = 0; r < ROWS; ++r) {
        const float vS  = waveRed(aS[r]);
        const float vD  = waveRed(aD[r]);
        const float vMS = waveRed(aMS[r]);
        const float vMD = waveRed(aMD[r]);
        if (lane == 0) {
            red[wave][r][0] = vS;
            red[wave][r][1] = vD;
            red[wave][r][2] = vMS;
            red[wave][r][3] = vMD;
        }
    }
    __syncthreads();

    if (t < ROWS) {
        float S = 0.f, D = 0.f, MS = 0.f, MD = 0.f;
#pragma unroll
        for (int w = 0; w < BLK / 64; ++w) {
            S  += red[w][t][0];
            D  += red[w][t][1];
            MS += red[w][t][2];
            MD += red[w][t][3];
        }
        const int   i  = r0 + t;
        const float bi = bias[i];

        const float lower     = fmaf(0.5f, S - D, bi);
        const float upper     = fmaf(0.5f, S + D, bi);
        const float new_lower = fmaf(0.5f, MS - MD, bi);
        const float new_upper = fmaf(0.5f, MS + MD, bi);

        out[i]         = fmaxf(lower, new_lower);
        out[N_OUT + i] = fminf(upper, new_upper);
    }
}

extern "C" void kernel_launch(void* const* d_in, const int* in_sizes, int n_in,
                              void* d_out, int out_size, void* d_ws, size_t ws_size,
                              hipStream_t stream) {
    const float* W       = (const float*)d_in[0];
    const float* bias    = (const float*)d_in[1];
    const float* bounds  = (const float*)d_in[2];
    const float* bounds0 = (const float*)d_in[3];
    const float* beta    = (const float*)d_in[4];
    const float* lmbda   = (const float*)d_in[5];
    const float* mu      = (const float*)d_in[6];
    float* out  = (float*)d_out;
    float* cols = (float*)d_ws;   // 4 * N_IN floats = 128 KB

    precompute_cols<<<N_IN / 256, 256, 0, stream>>>(
        bounds, bounds0, beta, lmbda, mu, cols);
    deeppoly_main<<<N_OUT / ROWS, BLK, 0, stream>>>(W, bias, cols, out);
}

// Round 4
// 36.070 us; speedup vs baseline: 2.2219x; 2.2219x over previous
//
#include <hip/hip_runtime.h>

// DeepPoly affine transformer — fused single pass over weight.
// Identity: Wp@x + Wm@y = 0.5*( W@(x+y) - |W|@(y-x) )
//           Wp@y + Wm@x = 0.5*( W@(x+y) + |W|@(y-x) )
// mu folded: new_lower = bias + sum( wp*A + wm*B ), A=beta*l0, B=lmbda*u0+mu
//            new_upper = bias + sum( wp*B + wm*A )
// Per weight element: 1 abs + 4 FMA against 4 precomputed column streams.
//
// R4: ROWS=8 (halves col re-reads vs ROWS=4), BLK=256, NO launch-bounds
// min-waves pin (R3's pin caused VGPR=64 + 101 MB scratch spill), and
// split-K=2 with a tiny epilogue to recover grid parallelism (col traffic
// is invariant under K-split; grid 512 -> 1024 blocks).

constexpr int N_OUT  = 4096;
constexpr int N_IN   = 8192;
constexpr int BLK    = 256;            // 4 waves
constexpr int ROWS   = 8;              // output rows per block
constexpr int SPLITK = 2;
constexpr int KSLICE = N_IN / SPLITK;            // 4096 columns per block
constexpr int KITER  = KSLICE / 4 / BLK;         // 4 float4 chunks per thread

__device__ __forceinline__ float4 ld4(const float* p) {
    return *reinterpret_cast<const float4*>(p);
}

__device__ __forceinline__ float waveRed(float v) {
#pragma unroll
    for (int off = 32; off > 0; off >>= 1)
        v += __shfl_xor(v, off, 64);
    return v;
}

// ---- pass 1: build the 4 fused column vectors into workspace ----
__global__ __launch_bounds__(256) void precompute_cols(
        const float* __restrict__ bounds,   // [2, N_IN]
        const float* __restrict__ bounds0,  // [2, N_IN]
        const float* __restrict__ beta,
        const float* __restrict__ lmbda,
        const float* __restrict__ mu,
        float* __restrict__ cols)           // [4, N_IN]
{
    const int i = blockIdx.x * 256 + threadIdx.x;
    if (i >= N_IN) return;
    const float l  = bounds[i],  u  = bounds[i + N_IN];
    const float l0 = bounds0[i], u0 = bounds0[i + N_IN];
    const float A  = beta[i] * l0;
    const float B  = fmaf(lmbda[i], u0, mu[i]);
    cols[i]             = l + u;   // s1
    cols[i + N_IN]      = u - l;   // d1  (>= 0)
    cols[i + 2 * N_IN]  = A + B;   // s2
    cols[i + 3 * N_IN]  = B - A;   // d2
}

// ---- pass 2: stream the weight once; write split-K partials ----
__global__ __launch_bounds__(BLK) void deeppoly_main(
        const float* __restrict__ W,
        const float* __restrict__ cols,
        float* __restrict__ partials)       // [SPLITK][N_OUT][4]
{
    const int t  = threadIdx.x;
    const int r0 = blockIdx.x * ROWS;
    const int sk = blockIdx.y;
    const int k0 = sk * KSLICE;

    const float* s1 = cols           + k0;
    const float* d1 = cols + N_IN    + k0;
    const float* s2 = cols + 2*N_IN  + k0;
    const float* d2 = cols + 3*N_IN  + k0;
    const float* Wb = W + (size_t)r0 * N_IN + k0;

    float aS[ROWS], aD[ROWS], aMS[ROWS], aMD[ROWS];
#pragma unroll
    for (int r = 0; r < ROWS; ++r) {
        aS[r] = 0.f; aD[r] = 0.f; aMS[r] = 0.f; aMD[r] = 0.f;
    }

#pragma unroll
    for (int k = 0; k < KITER; ++k) {
        const int c = (t + k * BLK) * 4;

        const float4 s1v = ld4(s1 + c);
        const float4 d1v = ld4(d1 + c);
        const float4 s2v = ld4(s2 + c);
        const float4 d2v = ld4(d2 + c);

#pragma unroll
        for (int r = 0; r < ROWS; ++r) {
            const float4 wv = ld4(Wb + (size_t)r * N_IN + c);

#define UPD(wc, s1c, d1c, s2c, d2c)                      \
            {                                            \
                const float w_ = (wc);                   \
                const float a_ = fabsf(w_);              \
                aS[r]  = fmaf(w_, (s1c), aS[r]);         \
                aD[r]  = fmaf(a_, (d1c), aD[r]);         \
                aMS[r] = fmaf(w_, (s2c), aMS[r]);        \
                aMD[r] = fmaf(a_, (d2c), aMD[r]);        \
            }
            UPD(wv.x, s1v.x, d1v.x, s2v.x, d2v.x)
            UPD(wv.y, s1v.y, d1v.y, s2v.y, d2v.y)
            UPD(wv.z, s1v.z, d1v.z, s2v.z, d2v.z)
            UPD(wv.w, s1v.w, d1v.w, s2v.w, d2v.w)
#undef UPD
        }
    }

    // ---- block reduction: wave shuffle-reduce, then LDS across 4 waves ----
    __shared__ float red[BLK / 64][ROWS][4];
    const int wave = t >> 6;
    const int lane = t & 63;

#pragma unroll
    for (int r = 0; r < ROWS; ++r) {
        const float vS  = waveRed(aS[r]);
        const float vD  = waveRed(aD[r]);
        const float vMS = waveRed(aMS[r]);
        const float vMD = waveRed(aMD[r]);
        if (lane == 0) {
            red[wave][r][0] = vS;
            red[wave][r][1] = vD;
            red[wave][r][2] = vMS;
            red[wave][r][3] = vMD;
        }
    }
    __syncthreads();

    // 32 threads write [row r, stream s] partial sums
    if (t < ROWS * 4) {
        const int r = t >> 2;
        const int s = t & 3;
        float acc = 0.f;
#pragma unroll
        for (int w = 0; w < BLK / 64; ++w)
            acc += red[w][r][s];
        // layout flattens to [sk][global_row][stream]
        partials[((size_t)sk * N_OUT + (r0 + r)) * 4 + s] = acc;
    }
}

// ---- pass 3: combine split-K partials + bias + tighter-bound select ----
__global__ __launch_bounds__(256) void deeppoly_epilogue(
        const float* __restrict__ partials, // [SPLITK][N_OUT][4]
        const float* __restrict__ bias,
        float* __restrict__ out)            // [2, N_OUT]
{
    const int i = blockIdx.x * 256 + threadIdx.x;
    if (i >= N_OUT) return;

    float4 p = ld4(partials + (size_t)i * 4);
#pragma unroll
    for (int sk = 1; sk < SPLITK; ++sk) {
        const float4 q = ld4(partials + ((size_t)sk * N_OUT + i) * 4);
        p.x += q.x; p.y += q.y; p.z += q.z; p.w += q.w;
    }
    const float bi = bias[i];
    const float lower     = fmaf(0.5f, p.x - p.y, bi);
    const float upper     = fmaf(0.5f, p.x + p.y, bi);
    const float new_lower = fmaf(0.5f, p.z - p.w, bi);
    const float new_upper = fmaf(0.5f, p.z + p.w, bi);

    out[i]         = fmaxf(lower, new_lower);
    out[N_OUT + i] = fminf(upper, new_upper);
}

extern "C" void kernel_launch(void* const* d_in, const int* in_sizes, int n_in,
                              void* d_out, int out_size, void* d_ws, size_t ws_size,
                              hipStream_t stream) {
    const float* W       = (const float*)d_in[0];
    const float* bias    = (const float*)d_in[1];
    const float* bounds  = (const float*)d_in[2];
    const float* bounds0 = (const float*)d_in[3];
    const float* beta    = (const float*)d_in[4];
    const float* lmbda   = (const float*)d_in[5];
    const float* mu      = (const float*)d_in[6];
    float* out      = (float*)d_out;
    float* cols     = (float*)d_ws;                       // 4*N_IN floats (128 KB)
    float* partials = (float*)d_ws + 4 * N_IN;            // SPLITK*N_OUT*4 floats (128 KB)

    precompute_cols<<<N_IN / 256, 256, 0, stream>>>(
        bounds, bounds0, beta, lmbda, mu, cols);

    dim3 grid(N_OUT / ROWS, SPLITK);
    deeppoly_main<<<grid, BLK, 0, stream>>>(W, cols, partials);

    deeppoly_epilogue<<<N_OUT / 256, 256, 0, stream>>>(partials, bias, out);
}